// Round 1
// baseline (416.619 us; speedup 1.0000x reference)
//
#include <hip/hip_runtime.h>
#include <hip/hip_bf16.h>

#define N_NODES 50000
#define N_EDGES 800000
#define DIM 128
#define N_GRAPHS 512

// ---------------- CSR build ----------------

__global__ void k_count(const int* __restrict__ ei, int* __restrict__ cnt, int E) {
    int e = blockIdx.x * 256 + threadIdx.x;
    if (e < E) atomicAdd(&cnt[ei[E + e]], 1);
}

// single-block inclusive/exclusive scan over n counts -> rowStart[n+1], also dinv = rsqrt(cnt+1)
__global__ void k_scan_deg(const int* __restrict__ cnt, int* __restrict__ rowStart,
                           float* __restrict__ dinv, int n) {
    __shared__ int wsum[16];
    __shared__ int carry_s;
    int tid = threadIdx.x;
    int lane = tid & 63, wv = tid >> 6;
    if (tid == 0) carry_s = 0;
    __syncthreads();
    for (int base = 0; base < n; base += 1024) {
        int i = base + tid;
        int v = (i < n) ? cnt[i] : 0;
        if (i < n) dinv[i] = rsqrtf((float)v + 1.0f);
        int s = v;
        #pragma unroll
        for (int off = 1; off < 64; off <<= 1) {
            int u = __shfl_up(s, off, 64);
            if (lane >= off) s += u;
        }
        if (lane == 63) wsum[wv] = s;
        __syncthreads();
        int carry = carry_s;
        int woff = 0;
        for (int w = 0; w < wv; ++w) woff += wsum[w];
        int excl = carry + woff + (s - v);
        if (i < n) rowStart[i] = excl;
        __syncthreads();
        if (tid == 0) {
            int tot = 0;
            for (int w = 0; w < 16; ++w) tot += wsum[w];
            carry_s = carry + tot;
        }
        __syncthreads();
    }
    if (tid == 0) rowStart[n] = carry_s;
}

__global__ void k_fill(const int* __restrict__ ei, const int* __restrict__ rowStart,
                       int* __restrict__ cursor, int* __restrict__ csr, int E) {
    int e = blockIdx.x * 256 + threadIdx.x;
    if (e < E) {
        int d = ei[E + e];
        int pos = rowStart[d] + atomicAdd(&cursor[d], 1);
        csr[pos] = ei[e];
    }
}

// ---------------- GEMM: out[r,:] = (X[r,:] @ W) * dinv[r] ----------------
// X:[N,128] W:[128,128] row-major. Block tile 128 rows; 256 thr; per-thread 8x8.

__global__ __launch_bounds__(256) void k_linscale(const float* __restrict__ X,
                                                  const float* __restrict__ W,
                                                  const float* __restrict__ dinv,
                                                  float* __restrict__ out, int N) {
    __shared__ float A[128 * 129];     // padded rows: stride 129 -> conflict-free b32 col reads
    __shared__ float Ws[128 * 128];
    int tid = threadIdx.x;
    int row0 = blockIdx.x * 128;

    // stage W (4096 float4)
    #pragma unroll
    for (int j = 0; j < 16; ++j) {
        int idx = j * 256 + tid;
        ((float4*)Ws)[idx] = ((const float4*)W)[idx];
    }
    // stage A (guarded, zero-fill tail rows)
    #pragma unroll
    for (int j = 0; j < 16; ++j) {
        int idx = j * 256 + tid;
        int r = idx >> 5;
        int c4 = (idx & 31) << 2;
        int gr = row0 + r;
        float4 v = make_float4(0.f, 0.f, 0.f, 0.f);
        if (gr < N) v = *(const float4*)(X + (size_t)gr * DIM + c4);
        float* dst = &A[r * 129 + c4];
        dst[0] = v.x; dst[1] = v.y; dst[2] = v.z; dst[3] = v.w;
    }
    __syncthreads();

    int rg = tid >> 4, cg = tid & 15;
    int m0 = rg * 8, n0 = cg * 8;
    float acc[8][8];
    #pragma unroll
    for (int i = 0; i < 8; ++i)
        #pragma unroll
        for (int j = 0; j < 8; ++j) acc[i][j] = 0.f;

    const float* Ar[8];
    #pragma unroll
    for (int i = 0; i < 8; ++i) Ar[i] = &A[(m0 + i) * 129];

    #pragma unroll 2
    for (int k = 0; k < 128; ++k) {
        float4 w0 = *(const float4*)&Ws[(k << 7) + n0];
        float4 w1 = *(const float4*)&Ws[(k << 7) + n0 + 4];
        float a[8];
        #pragma unroll
        for (int i = 0; i < 8; ++i) a[i] = Ar[i][k];
        #pragma unroll
        for (int i = 0; i < 8; ++i) {
            acc[i][0] += a[i] * w0.x;
            acc[i][1] += a[i] * w0.y;
            acc[i][2] += a[i] * w0.z;
            acc[i][3] += a[i] * w0.w;
            acc[i][4] += a[i] * w1.x;
            acc[i][5] += a[i] * w1.y;
            acc[i][6] += a[i] * w1.z;
            acc[i][7] += a[i] * w1.w;
        }
    }

    #pragma unroll
    for (int i = 0; i < 8; ++i) {
        int gr = row0 + m0 + i;
        if (gr < N) {
            float di = dinv[gr];
            float4 o0 = make_float4(acc[i][0] * di, acc[i][1] * di, acc[i][2] * di, acc[i][3] * di);
            float4 o1 = make_float4(acc[i][4] * di, acc[i][5] * di, acc[i][6] * di, acc[i][7] * di);
            *(float4*)(out + (size_t)gr * DIM + n0) = o0;
            *(float4*)(out + (size_t)gr * DIM + n0 + 4) = o1;
        }
    }
}

// ---------------- Aggregation: out[i] = relu(dinv[i]*(sum_in hs[src] + hs[i]) + b) ----------------
// one wave per node; lane holds float2 (cols 2l,2l+1)

__global__ __launch_bounds__(256) void k_aggregate(const float* __restrict__ HS,
                                                   const int* __restrict__ rowStart,
                                                   const int* __restrict__ csr,
                                                   const float* __restrict__ dinv,
                                                   const float* __restrict__ bias,
                                                   float* __restrict__ out, int n) {
    int wv = threadIdx.x >> 6, lane = threadIdx.x & 63;
    int nid = blockIdx.x * 4 + wv;
    if (nid >= n) return;
    const float2* selfp = (const float2*)(HS + (size_t)nid * DIM);
    float2 acc = selfp[lane];
    int beg = rowStart[nid], end = rowStart[nid + 1];
    int e = beg;
    for (; e + 1 < end; e += 2) {
        int s0 = csr[e], s1 = csr[e + 1];
        float2 v0 = ((const float2*)(HS + (size_t)s0 * DIM))[lane];
        float2 v1 = ((const float2*)(HS + (size_t)s1 * DIM))[lane];
        acc.x += v0.x + v1.x;
        acc.y += v0.y + v1.y;
    }
    if (e < end) {
        int s0 = csr[e];
        float2 v0 = ((const float2*)(HS + (size_t)s0 * DIM))[lane];
        acc.x += v0.x;
        acc.y += v0.y;
    }
    float di = dinv[nid];
    int c = lane * 2;
    float ox = fmaxf(acc.x * di + bias[c], 0.f);
    float oy = fmaxf(acc.y * di + bias[c + 1], 0.f);
    ((float2*)(out + (size_t)nid * DIM))[lane] = make_float2(ox, oy);
}

// ---------------- Pool + head: out[g] = (sum_{i in g} H[i,:] . Wl) / max(cnt,1) + bl ----------------

__global__ __launch_bounds__(128) void k_pool(const float* __restrict__ H,
                                              const int* __restrict__ batch,
                                              const float* __restrict__ Wl,
                                              const float* __restrict__ bl,
                                              float* __restrict__ out, int n) {
    int g = blockIdx.x;
    int lo = 0, hi = n;
    while (lo < hi) { int mid = (lo + hi) >> 1; if (batch[mid] < g) lo = mid + 1; else hi = mid; }
    int s = lo;
    hi = n;
    while (lo < hi) { int mid = (lo + hi) >> 1; if (batch[mid] < g + 1) lo = mid + 1; else hi = mid; }
    int e = lo;

    int d = threadIdx.x;  // 128 threads, one per column
    float colsum = 0.f;
    for (int i = s; i < e; ++i) colsum += H[(size_t)i * DIM + d];
    float v = colsum * Wl[d];

    #pragma unroll
    for (int off = 32; off > 0; off >>= 1) v += __shfl_down(v, off, 64);
    __shared__ float ws2[2];
    int lane = d & 63, wv = d >> 6;
    if (lane == 0) ws2[wv] = v;
    __syncthreads();
    if (d == 0) {
        float tot = ws2[0] + ws2[1];
        float cntf = (float)(e - s);
        out[g] = tot / fmaxf(cntf, 1.0f) + bl[0];
    }
}

// ---------------- launch ----------------

extern "C" void kernel_launch(void* const* d_in, const int* in_sizes, int n_in,
                              void* d_out, int out_size, void* d_ws, size_t ws_size,
                              hipStream_t stream) {
    const float* x  = (const float*)d_in[0];
    const int*   ei = (const int*)d_in[1];
    const int*   batch = (const int*)d_in[2];
    const float* W1 = (const float*)d_in[3];
    const float* b1 = (const float*)d_in[4];
    const float* W2 = (const float*)d_in[5];
    const float* b2 = (const float*)d_in[6];
    const float* Wl = (const float*)d_in[7];
    const float* bl = (const float*)d_in[8];
    float* out = (float*)d_out;

    // workspace layout
    float* hs   = (float*)d_ws;                       // N*128
    float* h2b  = hs + (size_t)N_NODES * DIM;         // N*128
    float* dinv = h2b + (size_t)N_NODES * DIM;        // N
    int* rowStart = (int*)(dinv + N_NODES);           // N+1 (pad to N+4)
    int* cnt    = rowStart + N_NODES + 4;             // N
    int* csr    = cnt + N_NODES;                      // E

    // 1. CSR build
    hipMemsetAsync(cnt, 0, N_NODES * sizeof(int), stream);
    k_count<<<(N_EDGES + 255) / 256, 256, 0, stream>>>(ei, cnt, N_EDGES);
    k_scan_deg<<<1, 1024, 0, stream>>>(cnt, rowStart, dinv, N_NODES);
    hipMemsetAsync(cnt, 0, N_NODES * sizeof(int), stream);
    k_fill<<<(N_EDGES + 255) / 256, 256, 0, stream>>>(ei, rowStart, cnt, csr, N_EDGES);

    int gemmGrid = (N_NODES + 127) / 128;
    int aggGrid  = (N_NODES + 3) / 4;

    // 2. layer 1
    k_linscale<<<gemmGrid, 256, 0, stream>>>(x, W1, dinv, hs, N_NODES);
    k_aggregate<<<aggGrid, 256, 0, stream>>>(hs, rowStart, csr, dinv, b1, h2b, N_NODES);

    // 3. layer 2
    k_linscale<<<gemmGrid, 256, 0, stream>>>(h2b, W2, dinv, hs, N_NODES);
    k_aggregate<<<aggGrid, 256, 0, stream>>>(hs, rowStart, csr, dinv, b2, h2b, N_NODES);

    // 4. pool + head
    k_pool<<<N_GRAPHS, 128, 0, stream>>>(h2b, batch, Wl, bl, out, N_NODES);
}

// Round 2
// 352.446 us; speedup vs baseline: 1.1821x; 1.1821x over previous
//
#include <hip/hip_runtime.h>
#include <hip/hip_bf16.h>

#define N_NODES 50000
#define N_EDGES 800000
#define DIM 128
#define N_GRAPHS 512
#define SCAN_BLK 1024
#define SCAN_NB ((N_NODES + SCAN_BLK - 1) / SCAN_BLK)   // 49

// ---------------- CSR build ----------------

__global__ void k_count(const int* __restrict__ ei, int* __restrict__ cnt, int E) {
    int e = blockIdx.x * 256 + threadIdx.x;
    if (e < E) atomicAdd(&cnt[ei[E + e]], 1);
}

// Phase A: per-block exclusive scan of counts + block totals + dinv
__global__ __launch_bounds__(1024) void k_scan_local(const int* __restrict__ cnt,
                                                     int* __restrict__ rowStart,
                                                     float* __restrict__ dinv,
                                                     int* __restrict__ blockSum, int n) {
    __shared__ int wsum[16];
    int tid = threadIdx.x;
    int i = blockIdx.x * SCAN_BLK + tid;
    int lane = tid & 63, wv = tid >> 6;
    int v = (i < n) ? cnt[i] : 0;
    if (i < n) dinv[i] = rsqrtf((float)v + 1.0f);
    int s = v;
    #pragma unroll
    for (int off = 1; off < 64; off <<= 1) {
        int u = __shfl_up(s, off, 64);
        if (lane >= off) s += u;
    }
    if (lane == 63) wsum[wv] = s;
    __syncthreads();
    int woff = 0;
    #pragma unroll
    for (int w = 0; w < 16; ++w) woff += (w < wv) ? wsum[w] : 0;
    if (i < n) rowStart[i] = woff + s - v;
    if (tid == 1023) blockSum[blockIdx.x] = woff + s;
}

// Phase B: one wave scans the 49 block sums in place -> exclusive offsets; writes total.
__global__ __launch_bounds__(64) void k_scan_bsums(int* __restrict__ blockSum,
                                                   int* __restrict__ rowStart, int n) {
    int tid = threadIdx.x;
    int v = (tid < SCAN_NB) ? blockSum[tid] : 0;
    int s = v;
    #pragma unroll
    for (int off = 1; off < 64; off <<= 1) {
        int u = __shfl_up(s, off, 64);
        if (tid >= off) s += u;
    }
    if (tid < SCAN_NB) blockSum[tid] = s - v;   // exclusive offset
    if (tid == 63) rowStart[n] = s;             // total (v=0 past SCAN_NB)
}

// Phase C: add block offsets
__global__ __launch_bounds__(1024) void k_scan_add(int* __restrict__ rowStart,
                                                   const int* __restrict__ blockSum, int n) {
    int i = blockIdx.x * SCAN_BLK + threadIdx.x;
    if (i < n && blockIdx.x > 0) rowStart[i] += blockSum[blockIdx.x];
}

__global__ void k_fill(const int* __restrict__ ei, const int* __restrict__ rowStart,
                       int* __restrict__ cursor, int* __restrict__ csr, int E) {
    int e = blockIdx.x * 256 + threadIdx.x;
    if (e < E) {
        int d = ei[E + e];
        int pos = rowStart[d] + atomicAdd(&cursor[d], 1);
        csr[pos] = ei[e];
    }
}

// ---------------- GEMM: out[r,:] = (X[r,:] @ W) * dinv[r] ----------------

__global__ __launch_bounds__(256) void k_linscale(const float* __restrict__ X,
                                                  const float* __restrict__ W,
                                                  const float* __restrict__ dinv,
                                                  float* __restrict__ out, int N) {
    __shared__ float A[128 * 129];
    __shared__ float Ws[128 * 128];
    int tid = threadIdx.x;
    int row0 = blockIdx.x * 128;

    #pragma unroll
    for (int j = 0; j < 16; ++j) {
        int idx = j * 256 + tid;
        ((float4*)Ws)[idx] = ((const float4*)W)[idx];
    }
    #pragma unroll
    for (int j = 0; j < 16; ++j) {
        int idx = j * 256 + tid;
        int r = idx >> 5;
        int c4 = (idx & 31) << 2;
        int gr = row0 + r;
        float4 v = make_float4(0.f, 0.f, 0.f, 0.f);
        if (gr < N) v = *(const float4*)(X + (size_t)gr * DIM + c4);
        float* dst = &A[r * 129 + c4];
        dst[0] = v.x; dst[1] = v.y; dst[2] = v.z; dst[3] = v.w;
    }
    __syncthreads();

    int rg = tid >> 4, cg = tid & 15;
    int m0 = rg * 8, n0 = cg * 8;
    float acc[8][8];
    #pragma unroll
    for (int i = 0; i < 8; ++i)
        #pragma unroll
        for (int j = 0; j < 8; ++j) acc[i][j] = 0.f;

    const float* Ar[8];
    #pragma unroll
    for (int i = 0; i < 8; ++i) Ar[i] = &A[(m0 + i) * 129];

    #pragma unroll 2
    for (int k = 0; k < 128; ++k) {
        float4 w0 = *(const float4*)&Ws[(k << 7) + n0];
        float4 w1 = *(const float4*)&Ws[(k << 7) + n0 + 4];
        float a[8];
        #pragma unroll
        for (int i = 0; i < 8; ++i) a[i] = Ar[i][k];
        #pragma unroll
        for (int i = 0; i < 8; ++i) {
            acc[i][0] += a[i] * w0.x;
            acc[i][1] += a[i] * w0.y;
            acc[i][2] += a[i] * w0.z;
            acc[i][3] += a[i] * w0.w;
            acc[i][4] += a[i] * w1.x;
            acc[i][5] += a[i] * w1.y;
            acc[i][6] += a[i] * w1.z;
            acc[i][7] += a[i] * w1.w;
        }
    }

    #pragma unroll
    for (int i = 0; i < 8; ++i) {
        int gr = row0 + m0 + i;
        if (gr < N) {
            float di = dinv[gr];
            float4 o0 = make_float4(acc[i][0] * di, acc[i][1] * di, acc[i][2] * di, acc[i][3] * di);
            float4 o1 = make_float4(acc[i][4] * di, acc[i][5] * di, acc[i][6] * di, acc[i][7] * di);
            *(float4*)(out + (size_t)gr * DIM + n0) = o0;
            *(float4*)(out + (size_t)gr * DIM + n0 + 4) = o1;
        }
    }
}

// ---------------- Aggregation ----------------

__global__ __launch_bounds__(256) void k_aggregate(const float* __restrict__ HS,
                                                   const int* __restrict__ rowStart,
                                                   const int* __restrict__ csr,
                                                   const float* __restrict__ dinv,
                                                   const float* __restrict__ bias,
                                                   float* __restrict__ out, int n) {
    int wv = threadIdx.x >> 6, lane = threadIdx.x & 63;
    int nid = blockIdx.x * 4 + wv;
    if (nid >= n) return;
    const float2* selfp = (const float2*)(HS + (size_t)nid * DIM);
    float2 acc = selfp[lane];
    int beg = rowStart[nid], end = rowStart[nid + 1];
    int e = beg;
    for (; e + 1 < end; e += 2) {
        int s0 = csr[e], s1 = csr[e + 1];
        float2 v0 = ((const float2*)(HS + (size_t)s0 * DIM))[lane];
        float2 v1 = ((const float2*)(HS + (size_t)s1 * DIM))[lane];
        acc.x += v0.x + v1.x;
        acc.y += v0.y + v1.y;
    }
    if (e < end) {
        int s0 = csr[e];
        float2 v0 = ((const float2*)(HS + (size_t)s0 * DIM))[lane];
        acc.x += v0.x;
        acc.y += v0.y;
    }
    float di = dinv[nid];
    int c = lane * 2;
    float ox = fmaxf(acc.x * di + bias[c], 0.f);
    float oy = fmaxf(acc.y * di + bias[c + 1], 0.f);
    ((float2*)(out + (size_t)nid * DIM))[lane] = make_float2(ox, oy);
}

// ---------------- Pool + head ----------------

__global__ __launch_bounds__(128) void k_pool(const float* __restrict__ H,
                                              const int* __restrict__ batch,
                                              const float* __restrict__ Wl,
                                              const float* __restrict__ bl,
                                              float* __restrict__ out, int n) {
    int g = blockIdx.x;
    int lo = 0, hi = n;
    while (lo < hi) { int mid = (lo + hi) >> 1; if (batch[mid] < g) lo = mid + 1; else hi = mid; }
    int s = lo;
    hi = n;
    while (lo < hi) { int mid = (lo + hi) >> 1; if (batch[mid] < g + 1) lo = mid + 1; else hi = mid; }
    int e = lo;

    int d = threadIdx.x;
    float colsum = 0.f;
    for (int i = s; i < e; ++i) colsum += H[(size_t)i * DIM + d];
    float v = colsum * Wl[d];

    #pragma unroll
    for (int off = 32; off > 0; off >>= 1) v += __shfl_down(v, off, 64);
    __shared__ float ws2[2];
    int lane = d & 63, wv = d >> 6;
    if (lane == 0) ws2[wv] = v;
    __syncthreads();
    if (d == 0) {
        float tot = ws2[0] + ws2[1];
        float cntf = (float)(e - s);
        out[g] = tot / fmaxf(cntf, 1.0f) + bl[0];
    }
}

// ---------------- launch ----------------

extern "C" void kernel_launch(void* const* d_in, const int* in_sizes, int n_in,
                              void* d_out, int out_size, void* d_ws, size_t ws_size,
                              hipStream_t stream) {
    const float* x  = (const float*)d_in[0];
    const int*   ei = (const int*)d_in[1];
    const int*   batch = (const int*)d_in[2];
    const float* W1 = (const float*)d_in[3];
    const float* b1 = (const float*)d_in[4];
    const float* W2 = (const float*)d_in[5];
    const float* b2 = (const float*)d_in[6];
    const float* Wl = (const float*)d_in[7];
    const float* bl = (const float*)d_in[8];
    float* out = (float*)d_out;

    // workspace layout
    float* hs   = (float*)d_ws;                       // N*128
    float* h2b  = hs + (size_t)N_NODES * DIM;         // N*128
    float* dinv = h2b + (size_t)N_NODES * DIM;        // N
    int* rowStart = (int*)(dinv + N_NODES);           // N+1 (pad to N+4)
    int* cnt    = rowStart + N_NODES + 4;             // N
    int* cursor = cnt + N_NODES;                      // N  (adjacent: one memset covers both)
    int* blockSum = cursor + N_NODES;                 // 64
    int* csr    = blockSum + 64;                      // E

    // 1. CSR build
    hipMemsetAsync(cnt, 0, 2 * N_NODES * sizeof(int), stream);  // cnt + cursor
    k_count<<<(N_EDGES + 255) / 256, 256, 0, stream>>>(ei, cnt, N_EDGES);
    k_scan_local<<<SCAN_NB, SCAN_BLK, 0, stream>>>(cnt, rowStart, dinv, blockSum, N_NODES);
    k_scan_bsums<<<1, 64, 0, stream>>>(blockSum, rowStart, N_NODES);
    k_scan_add<<<SCAN_NB, SCAN_BLK, 0, stream>>>(rowStart, blockSum, N_NODES);
    k_fill<<<(N_EDGES + 255) / 256, 256, 0, stream>>>(ei, rowStart, cursor, csr, N_EDGES);

    int gemmGrid = (N_NODES + 127) / 128;
    int aggGrid  = (N_NODES + 3) / 4;

    // 2. layer 1
    k_linscale<<<gemmGrid, 256, 0, stream>>>(x, W1, dinv, hs, N_NODES);
    k_aggregate<<<aggGrid, 256, 0, stream>>>(hs, rowStart, csr, dinv, b1, h2b, N_NODES);

    // 3. layer 2
    k_linscale<<<gemmGrid, 256, 0, stream>>>(h2b, W2, dinv, hs, N_NODES);
    k_aggregate<<<aggGrid, 256, 0, stream>>>(hs, rowStart, csr, dinv, b2, h2b, N_NODES);

    // 4. pool + head
    k_pool<<<N_GRAPHS, 128, 0, stream>>>(h2b, batch, Wl, bl, out, N_NODES);
}

// Round 3
// 303.222 us; speedup vs baseline: 1.3740x; 1.1623x over previous
//
#include <hip/hip_runtime.h>
#include <hip/hip_bf16.h>

#define N_NODES 50000
#define N_EDGES 800000
#define DIM 128
#define N_GRAPHS 512
#define SCAN_BLK 1024
#define SCAN_NB ((N_NODES + SCAN_BLK - 1) / SCAN_BLK)   // 49

typedef unsigned int uint;
typedef unsigned short ushort;

__device__ __forceinline__ ushort f2bf(float f) {
    uint u = __float_as_uint(f);
    uint r = (u + 0x7FFF + ((u >> 16) & 1)) >> 16;   // round-to-nearest-even
    return (ushort)r;
}
__device__ __forceinline__ float bf2f(ushort h) {
    return __uint_as_float(((uint)h) << 16);
}
__device__ __forceinline__ uint pack2(float a, float b) {
    return (uint)f2bf(a) | ((uint)f2bf(b) << 16);
}
__device__ __forceinline__ float2 unpack2(uint v) {
    return make_float2(__uint_as_float(v << 16), __uint_as_float(v & 0xFFFF0000u));
}

// ---------------- CSR build ----------------

__global__ void k_count(const int* __restrict__ ei, int* __restrict__ cnt, int E) {
    int e = blockIdx.x * 256 + threadIdx.x;
    if (e < E) atomicAdd(&cnt[ei[E + e]], 1);
}

__global__ __launch_bounds__(1024) void k_scan_local(const int* __restrict__ cnt,
                                                     int* __restrict__ rowStart,
                                                     float* __restrict__ dinv,
                                                     int* __restrict__ blockSum, int n) {
    __shared__ int wsum[16];
    int tid = threadIdx.x;
    int i = blockIdx.x * SCAN_BLK + tid;
    int lane = tid & 63, wv = tid >> 6;
    int v = (i < n) ? cnt[i] : 0;
    if (i < n) dinv[i] = rsqrtf((float)v + 1.0f);
    int s = v;
    #pragma unroll
    for (int off = 1; off < 64; off <<= 1) {
        int u = __shfl_up(s, off, 64);
        if (lane >= off) s += u;
    }
    if (lane == 63) wsum[wv] = s;
    __syncthreads();
    int woff = 0;
    #pragma unroll
    for (int w = 0; w < 16; ++w) woff += (w < wv) ? wsum[w] : 0;
    if (i < n) rowStart[i] = woff + s - v;
    if (tid == 1023) blockSum[blockIdx.x] = woff + s;
}

__global__ __launch_bounds__(64) void k_scan_bsums(int* __restrict__ blockSum,
                                                   int* __restrict__ rowStart, int n) {
    int tid = threadIdx.x;
    int v = (tid < SCAN_NB) ? blockSum[tid] : 0;
    int s = v;
    #pragma unroll
    for (int off = 1; off < 64; off <<= 1) {
        int u = __shfl_up(s, off, 64);
        if (tid >= off) s += u;
    }
    if (tid < SCAN_NB) blockSum[tid] = s - v;
    if (tid == 63) rowStart[n] = s;
}

__global__ __launch_bounds__(1024) void k_scan_add(int* __restrict__ rowStart,
                                                   const int* __restrict__ blockSum, int n) {
    int i = blockIdx.x * SCAN_BLK + threadIdx.x;
    if (i < n && blockIdx.x > 0) rowStart[i] += blockSum[blockIdx.x];
}

__global__ void k_fill(const int* __restrict__ ei, const int* __restrict__ rowStart,
                       int* __restrict__ cursor, int* __restrict__ csr, int E) {
    int e = blockIdx.x * 256 + threadIdx.x;
    if (e < E) {
        int d = ei[E + e];
        int pos = rowStart[d] + atomicAdd(&cursor[d], 1);
        csr[pos] = ei[e];
    }
}

// ---------------- GEMM kernels: out_bf16[r,:] = (X[r,:] @ W) * dinv[r] ----------------
// 128-row tile, 256 threads, per-thread 8x8 f32 acc. Output packed bf16.

__global__ __launch_bounds__(256) void k_lin_f32in(const float* __restrict__ X,
                                                   const float* __restrict__ W,
                                                   const float* __restrict__ dinv,
                                                   uint* __restrict__ out, int N) {
    __shared__ float A[128 * 129];
    __shared__ float Ws[128 * 128];
    int tid = threadIdx.x;
    int row0 = blockIdx.x * 128;

    #pragma unroll
    for (int j = 0; j < 16; ++j) {
        int idx = j * 256 + tid;
        ((float4*)Ws)[idx] = ((const float4*)W)[idx];
    }
    #pragma unroll
    for (int j = 0; j < 16; ++j) {
        int idx = j * 256 + tid;
        int r = idx >> 5;
        int c4 = (idx & 31) << 2;
        int gr = row0 + r;
        float4 v = make_float4(0.f, 0.f, 0.f, 0.f);
        if (gr < N) v = *(const float4*)(X + (size_t)gr * DIM + c4);
        float* dst = &A[r * 129 + c4];
        dst[0] = v.x; dst[1] = v.y; dst[2] = v.z; dst[3] = v.w;
    }
    __syncthreads();

    int rg = tid >> 4, cg = tid & 15;
    int m0 = rg * 8, n0 = cg * 8;
    float acc[8][8];
    #pragma unroll
    for (int i = 0; i < 8; ++i)
        #pragma unroll
        for (int j = 0; j < 8; ++j) acc[i][j] = 0.f;

    const float* Ar[8];
    #pragma unroll
    for (int i = 0; i < 8; ++i) Ar[i] = &A[(m0 + i) * 129];

    #pragma unroll 2
    for (int k = 0; k < 128; ++k) {
        float4 w0 = *(const float4*)&Ws[(k << 7) + n0];
        float4 w1 = *(const float4*)&Ws[(k << 7) + n0 + 4];
        float a[8];
        #pragma unroll
        for (int i = 0; i < 8; ++i) a[i] = Ar[i][k];
        #pragma unroll
        for (int i = 0; i < 8; ++i) {
            acc[i][0] += a[i] * w0.x;
            acc[i][1] += a[i] * w0.y;
            acc[i][2] += a[i] * w0.z;
            acc[i][3] += a[i] * w0.w;
            acc[i][4] += a[i] * w1.x;
            acc[i][5] += a[i] * w1.y;
            acc[i][6] += a[i] * w1.z;
            acc[i][7] += a[i] * w1.w;
        }
    }

    #pragma unroll
    for (int i = 0; i < 8; ++i) {
        int gr = row0 + m0 + i;
        if (gr < N) {
            float di = dinv[gr];
            uint4 o;
            o.x = pack2(acc[i][0] * di, acc[i][1] * di);
            o.y = pack2(acc[i][2] * di, acc[i][3] * di);
            o.z = pack2(acc[i][4] * di, acc[i][5] * di);
            o.w = pack2(acc[i][6] * di, acc[i][7] * di);
            *(uint4*)(out + (size_t)gr * 64 + (n0 >> 1)) = o;
        }
    }
}

__global__ __launch_bounds__(256) void k_lin_bf16in(const uint* __restrict__ Xb,   // bf16 pairs
                                                    const float* __restrict__ W,
                                                    const float* __restrict__ dinv,
                                                    uint* __restrict__ out, int N) {
    __shared__ float A[128 * 129];
    __shared__ float Ws[128 * 128];
    int tid = threadIdx.x;
    int row0 = blockIdx.x * 128;

    #pragma unroll
    for (int j = 0; j < 16; ++j) {
        int idx = j * 256 + tid;
        ((float4*)Ws)[idx] = ((const float4*)W)[idx];
    }
    // stage A: 128 rows x 16 chunks of 8 bf16 (uint4)
    #pragma unroll
    for (int j = 0; j < 8; ++j) {
        int idx = j * 256 + tid;         // 2048 chunks
        int r = idx >> 4;
        int c8 = (idx & 15) << 3;        // col start (elements)
        int gr = row0 + r;
        uint4 v = make_uint4(0, 0, 0, 0);
        if (gr < N) v = *(const uint4*)(Xb + (size_t)gr * 64 + (c8 >> 1));
        float* dst = &A[r * 129 + c8];
        float2 p0 = unpack2(v.x), p1 = unpack2(v.y), p2 = unpack2(v.z), p3 = unpack2(v.w);
        dst[0] = p0.x; dst[1] = p0.y; dst[2] = p1.x; dst[3] = p1.y;
        dst[4] = p2.x; dst[5] = p2.y; dst[6] = p3.x; dst[7] = p3.y;
    }
    __syncthreads();

    int rg = tid >> 4, cg = tid & 15;
    int m0 = rg * 8, n0 = cg * 8;
    float acc[8][8];
    #pragma unroll
    for (int i = 0; i < 8; ++i)
        #pragma unroll
        for (int j = 0; j < 8; ++j) acc[i][j] = 0.f;

    const float* Ar[8];
    #pragma unroll
    for (int i = 0; i < 8; ++i) Ar[i] = &A[(m0 + i) * 129];

    #pragma unroll 2
    for (int k = 0; k < 128; ++k) {
        float4 w0 = *(const float4*)&Ws[(k << 7) + n0];
        float4 w1 = *(const float4*)&Ws[(k << 7) + n0 + 4];
        float a[8];
        #pragma unroll
        for (int i = 0; i < 8; ++i) a[i] = Ar[i][k];
        #pragma unroll
        for (int i = 0; i < 8; ++i) {
            acc[i][0] += a[i] * w0.x;
            acc[i][1] += a[i] * w0.y;
            acc[i][2] += a[i] * w0.z;
            acc[i][3] += a[i] * w0.w;
            acc[i][4] += a[i] * w1.x;
            acc[i][5] += a[i] * w1.y;
            acc[i][6] += a[i] * w1.z;
            acc[i][7] += a[i] * w1.w;
        }
    }

    #pragma unroll
    for (int i = 0; i < 8; ++i) {
        int gr = row0 + m0 + i;
        if (gr < N) {
            float di = dinv[gr];
            uint4 o;
            o.x = pack2(acc[i][0] * di, acc[i][1] * di);
            o.y = pack2(acc[i][2] * di, acc[i][3] * di);
            o.z = pack2(acc[i][4] * di, acc[i][5] * di);
            o.w = pack2(acc[i][6] * di, acc[i][7] * di);
            *(uint4*)(out + (size_t)gr * 64 + (n0 >> 1)) = o;
        }
    }
}

// ---------------- Aggregation (bf16 rows, f32 accumulate) ----------------
// one wave per node; lane holds cols (2l, 2l+1) as packed bf16

__global__ __launch_bounds__(256) void k_aggregate(const uint* __restrict__ HS,
                                                   const int* __restrict__ rowStart,
                                                   const int* __restrict__ csr,
                                                   const float* __restrict__ dinv,
                                                   const float* __restrict__ bias,
                                                   uint* __restrict__ out, int n) {
    int wv = threadIdx.x >> 6, lane = threadIdx.x & 63;
    int nid = blockIdx.x * 4 + wv;
    if (nid >= n) return;
    uint sv = HS[(size_t)nid * 64 + lane];
    float2 acc = unpack2(sv);
    int beg = rowStart[nid], end = rowStart[nid + 1];
    int e = beg;
    for (; e + 3 < end; e += 4) {
        int s0 = csr[e], s1 = csr[e + 1], s2 = csr[e + 2], s3 = csr[e + 3];
        uint v0 = HS[(size_t)s0 * 64 + lane];
        uint v1 = HS[(size_t)s1 * 64 + lane];
        uint v2 = HS[(size_t)s2 * 64 + lane];
        uint v3 = HS[(size_t)s3 * 64 + lane];
        float2 f0 = unpack2(v0), f1 = unpack2(v1), f2 = unpack2(v2), f3 = unpack2(v3);
        acc.x += (f0.x + f1.x) + (f2.x + f3.x);
        acc.y += (f0.y + f1.y) + (f2.y + f3.y);
    }
    for (; e < end; ++e) {
        uint v0 = HS[(size_t)csr[e] * 64 + lane];
        float2 f0 = unpack2(v0);
        acc.x += f0.x;
        acc.y += f0.y;
    }
    float di = dinv[nid];
    int c = lane * 2;
    float ox = fmaxf(acc.x * di + bias[c], 0.f);
    float oy = fmaxf(acc.y * di + bias[c + 1], 0.f);
    out[(size_t)nid * 64 + lane] = pack2(ox, oy);
}

// ---------------- Pool + head ----------------

__global__ __launch_bounds__(128) void k_pool(const ushort* __restrict__ H,   // bf16
                                              const int* __restrict__ batch,
                                              const float* __restrict__ Wl,
                                              const float* __restrict__ bl,
                                              float* __restrict__ out, int n) {
    int g = blockIdx.x;
    int lo = 0, hi = n;
    while (lo < hi) { int mid = (lo + hi) >> 1; if (batch[mid] < g) lo = mid + 1; else hi = mid; }
    int s = lo;
    hi = n;
    while (lo < hi) { int mid = (lo + hi) >> 1; if (batch[mid] < g + 1) lo = mid + 1; else hi = mid; }
    int e = lo;

    int d = threadIdx.x;
    float colsum = 0.f;
    for (int i = s; i < e; ++i) colsum += bf2f(H[(size_t)i * DIM + d]);
    float v = colsum * Wl[d];

    #pragma unroll
    for (int off = 32; off > 0; off >>= 1) v += __shfl_down(v, off, 64);
    __shared__ float ws2[2];
    int lane = d & 63, wv = d >> 6;
    if (lane == 0) ws2[wv] = v;
    __syncthreads();
    if (d == 0) {
        float tot = ws2[0] + ws2[1];
        float cntf = (float)(e - s);
        out[g] = tot / fmaxf(cntf, 1.0f) + bl[0];
    }
}

// ---------------- launch ----------------

extern "C" void kernel_launch(void* const* d_in, const int* in_sizes, int n_in,
                              void* d_out, int out_size, void* d_ws, size_t ws_size,
                              hipStream_t stream) {
    const float* x  = (const float*)d_in[0];
    const int*   ei = (const int*)d_in[1];
    const int*   batch = (const int*)d_in[2];
    const float* W1 = (const float*)d_in[3];
    const float* b1 = (const float*)d_in[4];
    const float* W2 = (const float*)d_in[5];
    const float* b2 = (const float*)d_in[6];
    const float* Wl = (const float*)d_in[7];
    const float* bl = (const float*)d_in[8];
    float* out = (float*)d_out;

    // workspace layout (bf16 features stored as uint pairs)
    uint* hs  = (uint*)d_ws;                          // N*64 uints (bf16 x128)
    uint* h2b = hs + (size_t)N_NODES * 64;            // N*64 uints
    float* dinv = (float*)(h2b + (size_t)N_NODES * 64); // N
    int* rowStart = (int*)(dinv + N_NODES);           // N+1 (pad 4)
    int* cnt    = rowStart + N_NODES + 4;             // N
    int* cursor = cnt + N_NODES;                      // N
    int* blockSum = cursor + N_NODES;                 // 64
    int* csr    = blockSum + 64;                      // E

    // 1. CSR build
    hipMemsetAsync(cnt, 0, 2 * N_NODES * sizeof(int), stream);
    k_count<<<(N_EDGES + 255) / 256, 256, 0, stream>>>(ei, cnt, N_EDGES);
    k_scan_local<<<SCAN_NB, SCAN_BLK, 0, stream>>>(cnt, rowStart, dinv, blockSum, N_NODES);
    k_scan_bsums<<<1, 64, 0, stream>>>(blockSum, rowStart, N_NODES);
    k_scan_add<<<SCAN_NB, SCAN_BLK, 0, stream>>>(rowStart, blockSum, N_NODES);
    k_fill<<<(N_EDGES + 255) / 256, 256, 0, stream>>>(ei, rowStart, cursor, csr, N_EDGES);

    int gemmGrid = (N_NODES + 127) / 128;
    int aggGrid  = (N_NODES + 3) / 4;

    // 2. layer 1
    k_lin_f32in<<<gemmGrid, 256, 0, stream>>>(x, W1, dinv, hs, N_NODES);
    k_aggregate<<<aggGrid, 256, 0, stream>>>(hs, rowStart, csr, dinv, b1, h2b, N_NODES);

    // 3. layer 2
    k_lin_bf16in<<<gemmGrid, 256, 0, stream>>>(h2b, W2, dinv, hs, N_NODES);
    k_aggregate<<<aggGrid, 256, 0, stream>>>(hs, rowStart, csr, dinv, b2, h2b, N_NODES);

    // 4. pool + head
    k_pool<<<N_GRAPHS, 128, 0, stream>>>((const ushort*)h2b, batch, Wl, bl, out, N_NODES);
}

// Round 4
// 248.748 us; speedup vs baseline: 1.6749x; 1.2190x over previous
//
#include <hip/hip_runtime.h>
#include <hip/hip_bf16.h>

#define N_NODES 50000
#define N_EDGES 800000
#define DIM 128
#define N_GRAPHS 512
#define SCAN_BLK 1024
#define SCAN_NB ((N_NODES + SCAN_BLK - 1) / SCAN_BLK)   // 49

typedef unsigned int uint;
typedef unsigned short ushort;
typedef __attribute__((ext_vector_type(8))) short short8;   // 8 x bf16 MFMA frag
typedef __attribute__((ext_vector_type(4))) float f32x4;    // MFMA C/D frag

__device__ __forceinline__ ushort f2bf(float f) {
    uint u = __float_as_uint(f);
    uint r = (u + 0x7FFF + ((u >> 16) & 1)) >> 16;   // round-to-nearest-even
    return (ushort)r;
}
__device__ __forceinline__ float bf2f(ushort h) {
    return __uint_as_float(((uint)h) << 16);
}
__device__ __forceinline__ uint pack2(float a, float b) {
    return (uint)f2bf(a) | ((uint)f2bf(b) << 16);
}
__device__ __forceinline__ float2 unpack2(uint v) {
    return make_float2(__uint_as_float(v << 16), __uint_as_float(v & 0xFFFF0000u));
}

// ---------------- CSR build ----------------

__global__ void k_count(const int* __restrict__ ei, int* __restrict__ cnt, int E) {
    int e = blockIdx.x * 256 + threadIdx.x;
    if (e < E) atomicAdd(&cnt[ei[E + e]], 1);
}

__global__ __launch_bounds__(1024) void k_scan_local(const int* __restrict__ cnt,
                                                     int* __restrict__ rowStart,
                                                     float* __restrict__ dinv,
                                                     int* __restrict__ blockSum, int n) {
    __shared__ int wsum[16];
    int tid = threadIdx.x;
    int i = blockIdx.x * SCAN_BLK + tid;
    int lane = tid & 63, wv = tid >> 6;
    int v = (i < n) ? cnt[i] : 0;
    if (i < n) dinv[i] = rsqrtf((float)v + 1.0f);
    int s = v;
    #pragma unroll
    for (int off = 1; off < 64; off <<= 1) {
        int u = __shfl_up(s, off, 64);
        if (lane >= off) s += u;
    }
    if (lane == 63) wsum[wv] = s;
    __syncthreads();
    int woff = 0;
    #pragma unroll
    for (int w = 0; w < 16; ++w) woff += (w < wv) ? wsum[w] : 0;
    if (i < n) rowStart[i] = woff + s - v;
    if (tid == 1023) blockSum[blockIdx.x] = woff + s;
}

__global__ __launch_bounds__(64) void k_scan_bsums(int* __restrict__ blockSum,
                                                   int* __restrict__ rowStart, int n) {
    int tid = threadIdx.x;
    int v = (tid < SCAN_NB) ? blockSum[tid] : 0;
    int s = v;
    #pragma unroll
    for (int off = 1; off < 64; off <<= 1) {
        int u = __shfl_up(s, off, 64);
        if (tid >= off) s += u;
    }
    if (tid < SCAN_NB) blockSum[tid] = s - v;
    if (tid == 63) rowStart[n] = s;
}

__global__ __launch_bounds__(1024) void k_scan_add(int* __restrict__ rowStart,
                                                   const int* __restrict__ blockSum, int n) {
    int i = blockIdx.x * SCAN_BLK + threadIdx.x;
    if (i < n && blockIdx.x > 0) rowStart[i] += blockSum[blockIdx.x];
}

__global__ void k_fill(const int* __restrict__ ei, const int* __restrict__ rowStart,
                       int* __restrict__ cursor, int* __restrict__ csr, int E) {
    int e = blockIdx.x * 256 + threadIdx.x;
    if (e < E) {
        int d = ei[E + e];
        int pos = rowStart[d] + atomicAdd(&cursor[d], 1);
        csr[pos] = ei[e];
    }
}

// ---------------- W -> MFMA B-fragment order (bf16), both layers in one kernel --------
// Wfrag uint index r = ((ct*4+kc)*64 + lane)*4 + j2 ; element j=2*j2(+1) has
// k = kc*32 + (lane>>4)*8 + j , n = ct*16 + (lane&15).

__global__ __launch_bounds__(256) void k_wconv(const float* __restrict__ W1,
                                               const float* __restrict__ W2,
                                               uint* __restrict__ wf1,
                                               uint* __restrict__ wf2) {
    int t = blockIdx.x * 256 + threadIdx.x;      // [0, 16384)
    const float* W = (t < 8192) ? W1 : W2;
    uint* dst = (t < 8192) ? wf1 : wf2;
    int r = t & 8191;
    int j2 = r & 3;
    int lane = (r >> 2) & 63;
    int tk = r >> 8;                 // ct*4+kc
    int kc = tk & 3, ct = tk >> 2;
    int j = j2 * 2;
    int k = kc * 32 + (lane >> 4) * 8 + j;
    int n = ct * 16 + (lane & 15);
    dst[r] = pack2(W[k * 128 + n], W[(k + 1) * 128 + n]);
}

// ---------------- MFMA GEMM: out_bf16[r,:] = bf16(X[r,:]) @ Wfrag * dinv[r] ----------
// 4 waves/block, each wave owns a 16-row strip x 128 cols. No LDS.

template<bool BF16IN>
__global__ __launch_bounds__(256) void k_lin_mfma(const void* __restrict__ Xv,
                                                  const uint* __restrict__ Wfrag,
                                                  const float* __restrict__ dinv,
                                                  uint* __restrict__ out, int N) {
    int wv = threadIdx.x >> 6, lane = threadIdx.x & 63;
    int strip = blockIdx.x * 4 + wv;
    int row0 = strip * 16;
    if (row0 >= N) return;
    int m = lane & 15;        // A-row / D-col within tile
    int kg = lane >> 4;       // k-group
    int arow = row0 + m;
    bool valid = arow < N;

    short8 af[4];
    if constexpr (!BF16IN) {
        const float* X = (const float*)Xv;
        const float* base = X + (size_t)arow * DIM + kg * 8;
        #pragma unroll
        for (int kc = 0; kc < 4; ++kc) {
            float4 a0 = make_float4(0.f, 0.f, 0.f, 0.f), a1 = a0;
            if (valid) {
                a0 = *(const float4*)(base + kc * 32);
                a1 = *(const float4*)(base + kc * 32 + 4);
            }
            short8 f;
            f[0] = (short)f2bf(a0.x); f[1] = (short)f2bf(a0.y);
            f[2] = (short)f2bf(a0.z); f[3] = (short)f2bf(a0.w);
            f[4] = (short)f2bf(a1.x); f[5] = (short)f2bf(a1.y);
            f[6] = (short)f2bf(a1.z); f[7] = (short)f2bf(a1.w);
            af[kc] = f;
        }
    } else {
        const uint* X = (const uint*)Xv;
        const uint* base = X + (size_t)arow * 64 + kg * 4;
        #pragma unroll
        for (int kc = 0; kc < 4; ++kc) {
            union { uint4 u; short8 s; } cv;
            cv.u = valid ? *(const uint4*)(base + kc * 16) : make_uint4(0, 0, 0, 0);
            af[kc] = cv.s;
        }
    }

    f32x4 acc[8];
    #pragma unroll
    for (int ct = 0; ct < 8; ++ct) acc[ct] = (f32x4){0.f, 0.f, 0.f, 0.f};

    #pragma unroll
    for (int ct = 0; ct < 8; ++ct) {
        #pragma unroll
        for (int kc = 0; kc < 4; ++kc) {
            union { uint4 u; short8 s; } bv;
            bv.u = *(const uint4*)(Wfrag + ((size_t)(ct * 4 + kc) * 64 + lane) * 4);
            acc[ct] = __builtin_amdgcn_mfma_f32_16x16x32_bf16(af[kc], bv.s, acc[ct], 0, 0, 0);
        }
    }

    // epilogue: D row = kg*4 + reg, col = ct*16 + m
    ushort* ob = (ushort*)out;
    #pragma unroll
    for (int reg = 0; reg < 4; ++reg) {
        int orow = row0 + kg * 4 + reg;
        if (orow < N) {
            float di = dinv[orow];
            size_t rb = (size_t)orow * DIM + m;
            #pragma unroll
            for (int ct = 0; ct < 8; ++ct)
                ob[rb + ct * 16] = f2bf(acc[ct][reg] * di);
        }
    }
}

// ---------------- Aggregation (bf16 rows, f32 accumulate) ----------------

__global__ __launch_bounds__(256) void k_aggregate(const uint* __restrict__ HS,
                                                   const int* __restrict__ rowStart,
                                                   const int* __restrict__ csr,
                                                   const float* __restrict__ dinv,
                                                   const float* __restrict__ bias,
                                                   uint* __restrict__ out, int n) {
    int wv = threadIdx.x >> 6, lane = threadIdx.x & 63;
    int nid = blockIdx.x * 4 + wv;
    if (nid >= n) return;
    uint sv = HS[(size_t)nid * 64 + lane];
    float2 acc = unpack2(sv);
    int beg = rowStart[nid], end = rowStart[nid + 1];
    int e = beg;
    for (; e + 3 < end; e += 4) {
        int s0 = csr[e], s1 = csr[e + 1], s2 = csr[e + 2], s3 = csr[e + 3];
        uint v0 = HS[(size_t)s0 * 64 + lane];
        uint v1 = HS[(size_t)s1 * 64 + lane];
        uint v2 = HS[(size_t)s2 * 64 + lane];
        uint v3 = HS[(size_t)s3 * 64 + lane];
        float2 f0 = unpack2(v0), f1 = unpack2(v1), f2 = unpack2(v2), f3 = unpack2(v3);
        acc.x += (f0.x + f1.x) + (f2.x + f3.x);
        acc.y += (f0.y + f1.y) + (f2.y + f3.y);
    }
    for (; e < end; ++e) {
        uint v0 = HS[(size_t)csr[e] * 64 + lane];
        float2 f0 = unpack2(v0);
        acc.x += f0.x;
        acc.y += f0.y;
    }
    float di = dinv[nid];
    int c = lane * 2;
    float ox = fmaxf(acc.x * di + bias[c], 0.f);
    float oy = fmaxf(acc.y * di + bias[c + 1], 0.f);
    out[(size_t)nid * 64 + lane] = pack2(ox, oy);
}

// ---------------- Pool + head ----------------

__global__ __launch_bounds__(128) void k_pool(const ushort* __restrict__ H,
                                              const int* __restrict__ batch,
                                              const float* __restrict__ Wl,
                                              const float* __restrict__ bl,
                                              float* __restrict__ out, int n) {
    int g = blockIdx.x;
    int lo = 0, hi = n;
    while (lo < hi) { int mid = (lo + hi) >> 1; if (batch[mid] < g) lo = mid + 1; else hi = mid; }
    int s = lo;
    hi = n;
    while (lo < hi) { int mid = (lo + hi) >> 1; if (batch[mid] < g + 1) lo = mid + 1; else hi = mid; }
    int e = lo;

    int d = threadIdx.x;
    float colsum = 0.f;
    for (int i = s; i < e; ++i) colsum += bf2f(H[(size_t)i * DIM + d]);
    float v = colsum * Wl[d];

    #pragma unroll
    for (int off = 32; off > 0; off >>= 1) v += __shfl_down(v, off, 64);
    __shared__ float ws2[2];
    int lane = d & 63, wv = d >> 6;
    if (lane == 0) ws2[wv] = v;
    __syncthreads();
    if (d == 0) {
        float tot = ws2[0] + ws2[1];
        float cntf = (float)(e - s);
        out[g] = tot / fmaxf(cntf, 1.0f) + bl[0];
    }
}

// ---------------- launch ----------------

extern "C" void kernel_launch(void* const* d_in, const int* in_sizes, int n_in,
                              void* d_out, int out_size, void* d_ws, size_t ws_size,
                              hipStream_t stream) {
    const float* x  = (const float*)d_in[0];
    const int*   ei = (const int*)d_in[1];
    const int*   batch = (const int*)d_in[2];
    const float* W1 = (const float*)d_in[3];
    const float* b1 = (const float*)d_in[4];
    const float* W2 = (const float*)d_in[5];
    const float* b2 = (const float*)d_in[6];
    const float* Wl = (const float*)d_in[7];
    const float* bl = (const float*)d_in[8];
    float* out = (float*)d_out;

    // workspace layout (bf16 features stored as uint pairs)
    uint* hs  = (uint*)d_ws;                            // N*64 uints (bf16 x128)
    uint* h2b = hs + (size_t)N_NODES * 64;              // N*64 uints
    float* dinv = (float*)(h2b + (size_t)N_NODES * 64); // N
    int* rowStart = (int*)(dinv + N_NODES);             // N+1 (pad 4)
    int* cnt    = rowStart + N_NODES + 4;               // N
    int* cursor = cnt + N_NODES;                        // N
    int* blockSum = cursor + N_NODES;                   // 64
    int* csr    = blockSum + 64;                        // E
    uint* wf1   = (uint*)(csr + N_EDGES);               // 8192
    uint* wf2   = wf1 + 8192;                           // 8192

    // 0. weight conversion to MFMA fragment order
    k_wconv<<<64, 256, 0, stream>>>(W1, W2, wf1, wf2);

    // 1. CSR build
    hipMemsetAsync(cnt, 0, 2 * N_NODES * sizeof(int), stream);
    k_count<<<(N_EDGES + 255) / 256, 256, 0, stream>>>(ei, cnt, N_EDGES);
    k_scan_local<<<SCAN_NB, SCAN_BLK, 0, stream>>>(cnt, rowStart, dinv, blockSum, N_NODES);
    k_scan_bsums<<<1, 64, 0, stream>>>(blockSum, rowStart, N_NODES);
    k_scan_add<<<SCAN_NB, SCAN_BLK, 0, stream>>>(rowStart, blockSum, N_NODES);
    k_fill<<<(N_EDGES + 255) / 256, 256, 0, stream>>>(ei, rowStart, cursor, csr, N_EDGES);

    int strips = (N_NODES + 15) / 16;                   // 3125
    int gemmGrid = (strips + 3) / 4;                    // 782
    int aggGrid  = (N_NODES + 3) / 4;

    // 2. layer 1
    k_lin_mfma<false><<<gemmGrid, 256, 0, stream>>>(x, wf1, dinv, hs, N_NODES);
    k_aggregate<<<aggGrid, 256, 0, stream>>>(hs, rowStart, csr, dinv, b1, h2b, N_NODES);

    // 3. layer 2
    k_lin_mfma<true><<<gemmGrid, 256, 0, stream>>>(h2b, wf2, dinv, hs, N_NODES);
    k_aggregate<<<aggGrid, 256, 0, stream>>>(hs, rowStart, csr, dinv, b2, h2b, N_NODES);

    // 4. pool + head
    k_pool<<<N_GRAPHS, 128, 0, stream>>>((const ushort*)h2b, batch, Wl, bl, out, N_NODES);
}

// Round 5
// 198.291 us; speedup vs baseline: 2.1011x; 1.2545x over previous
//
#include <hip/hip_runtime.h>
#include <hip/hip_bf16.h>

#define N_NODES 50000
#define N_EDGES 800000
#define DIM 128
#define N_GRAPHS 512
#define NBUCK ((N_NODES + 63) / 64)      // 782 buckets of 64 nodes
#define SC_CH 16384                       // edges per scatter block

typedef unsigned int uint;
typedef unsigned short ushort;
typedef __attribute__((ext_vector_type(8))) short short8;   // 8 x bf16 MFMA frag
typedef __attribute__((ext_vector_type(4))) float f32x4;    // MFMA C/D frag

__device__ __forceinline__ ushort f2bf(float f) {
    uint u = __float_as_uint(f);
    uint r = (u + 0x7FFF + ((u >> 16) & 1)) >> 16;   // round-to-nearest-even
    return (ushort)r;
}
__device__ __forceinline__ float bf2f(ushort h) {
    return __uint_as_float(((uint)h) << 16);
}
__device__ __forceinline__ uint pack2(float a, float b) {
    return (uint)f2bf(a) | ((uint)f2bf(b) << 16);
}
__device__ __forceinline__ float2 unpack2(uint v) {
    return make_float2(__uint_as_float(v << 16), __uint_as_float(v & 0xFFFF0000u));
}

// ---------------- bucketed CSR build ----------------

// Pass 1: per-block LDS histogram of dst>>6 -> global bucketCnt
__global__ __launch_bounds__(1024) void k_bcount(const int* __restrict__ ei,
                                                 int* __restrict__ bucketCnt, int E) {
    __shared__ int h[NBUCK];
    int tid = threadIdx.x;
    for (int t = tid; t < NBUCK; t += 1024) h[t] = 0;
    __syncthreads();
    for (int e = blockIdx.x * 1024 + tid; e < E; e += gridDim.x * 1024)
        atomicAdd(&h[ei[E + e] >> 6], 1);
    __syncthreads();
    for (int t = tid; t < NBUCK; t += 1024) {
        int c = h[t];
        if (c) atomicAdd(&bucketCnt[t], c);
    }
}

// Pass 2: single-block scan of NBUCK counts -> bucketStart[NBUCK+1], bucketCursor copy
__global__ __launch_bounds__(1024) void k_bscan(const int* __restrict__ bucketCnt,
                                                int* __restrict__ bucketStart,
                                                int* __restrict__ bucketCursor) {
    __shared__ int wsum[16];
    int tid = threadIdx.x;
    int lane = tid & 63, wv = tid >> 6;
    int v = (tid < NBUCK) ? bucketCnt[tid] : 0;
    int s = v;
    #pragma unroll
    for (int off = 1; off < 64; off <<= 1) {
        int u = __shfl_up(s, off, 64);
        if (lane >= off) s += u;
    }
    if (lane == 63) wsum[wv] = s;
    __syncthreads();
    int woff = 0;
    #pragma unroll
    for (int w = 0; w < 16; ++w) woff += (w < wv) ? wsum[w] : 0;
    int excl = woff + s - v;
    if (tid < NBUCK) {
        bucketStart[tid] = excl;
        bucketCursor[tid] = excl;
    }
    if (tid == 1023) {
        int tot = 0;
        #pragma unroll
        for (int w = 0; w < 16; ++w) tot += wsum[w];
        bucketStart[NBUCK] = tot;
    }
}

// Pass 3: scatter (src,dst) pairs into bucket regions with block-local reservations
__global__ __launch_bounds__(1024) void k_bscatter(const int* __restrict__ ei,
                                                   int* __restrict__ bucketCursor,
                                                   uint2* __restrict__ epair, int E) {
    __shared__ int hc[NBUCK];
    __shared__ int hbase[NBUCK];
    int tid = threadIdx.x;
    int e0 = blockIdx.x * SC_CH;
    int e1 = min(e0 + SC_CH, E);
    for (int t = tid; t < NBUCK; t += 1024) hc[t] = 0;
    __syncthreads();
    for (int e = e0 + tid; e < e1; e += 1024)
        atomicAdd(&hc[ei[E + e] >> 6], 1);
    __syncthreads();
    for (int t = tid; t < NBUCK; t += 1024) {
        int c = hc[t];
        hbase[t] = c ? atomicAdd(&bucketCursor[t], c) : 0;
        hc[t] = 0;
    }
    __syncthreads();
    for (int e = e0 + tid; e < e1; e += 1024) {
        int s = ei[e], d = ei[E + e];
        int b = d >> 6;
        int off = atomicAdd(&hc[b], 1);
        epair[hbase[b] + off] = make_uint2((uint)s, (uint)d);
    }
}

// Pass 4: per-bucket local CSR: rowStart, dinv, csr fill (all writes in a ~4KB window)
__global__ __launch_bounds__(256) void k_localcsr(const uint2* __restrict__ epair,
                                                  const int* __restrict__ bucketStart,
                                                  int* __restrict__ rowStart,
                                                  float* __restrict__ dinv,
                                                  int* __restrict__ csr) {
    __shared__ int cnt[64];
    __shared__ int cur[64];
    int tid = threadIdx.x;
    int b = blockIdx.x;
    int b0 = b << 6;
    int s = bucketStart[b], e = bucketStart[b + 1];
    if (tid < 64) cnt[tid] = 0;
    __syncthreads();
    for (int i = s + tid; i < e; i += 256)
        atomicAdd(&cnt[epair[i].y - b0], 1);
    __syncthreads();
    if (tid < 64) {   // wave 0: 64-wide exclusive scan
        int c = cnt[tid];
        int sc = c;
        #pragma unroll
        for (int off = 1; off < 64; off <<= 1) {
            int u = __shfl_up(sc, off, 64);
            if (tid >= off) sc += u;
        }
        int excl = sc - c;
        int node = b0 + tid;
        if (node < N_NODES) {
            rowStart[node] = s + excl;
            dinv[node] = rsqrtf((float)c + 1.0f);
        }
        cur[tid] = s + excl;
    }
    if (tid == 0 && b == NBUCK - 1) rowStart[N_NODES] = e;
    __syncthreads();
    for (int i = s + tid; i < e; i += 256) {
        uint2 p = epair[i];
        int pos = atomicAdd(&cur[p.y - b0], 1);
        csr[pos] = (int)p.x;
    }
}

// ---------------- W -> MFMA B-fragment order (bf16) ----------------

__global__ __launch_bounds__(256) void k_wconv(const float* __restrict__ W1,
                                               const float* __restrict__ W2,
                                               uint* __restrict__ wf1,
                                               uint* __restrict__ wf2) {
    int t = blockIdx.x * 256 + threadIdx.x;      // [0, 16384)
    const float* W = (t < 8192) ? W1 : W2;
    uint* dst = (t < 8192) ? wf1 : wf2;
    int r = t & 8191;
    int j2 = r & 3;
    int lane = (r >> 2) & 63;
    int tk = r >> 8;                 // ct*4+kc
    int kc = tk & 3, ct = tk >> 2;
    int j = j2 * 2;
    int k = kc * 32 + (lane >> 4) * 8 + j;
    int n = ct * 16 + (lane & 15);
    dst[r] = pack2(W[k * 128 + n], W[(k + 1) * 128 + n]);
}

// ---------------- MFMA GEMM: out_bf16[r,:] = bf16(X[r,:]) @ Wfrag * dinv[r] ----------

template<bool BF16IN>
__global__ __launch_bounds__(256) void k_lin_mfma(const void* __restrict__ Xv,
                                                  const uint* __restrict__ Wfrag,
                                                  const float* __restrict__ dinv,
                                                  uint* __restrict__ out, int N) {
    int wv = threadIdx.x >> 6, lane = threadIdx.x & 63;
    int strip = blockIdx.x * 4 + wv;
    int row0 = strip * 16;
    if (row0 >= N) return;
    int m = lane & 15;        // A-row / D-col within tile
    int kg = lane >> 4;       // k-group
    int arow = row0 + m;
    bool valid = arow < N;

    short8 af[4];
    if constexpr (!BF16IN) {
        const float* X = (const float*)Xv;
        const float* base = X + (size_t)arow * DIM + kg * 8;
        #pragma unroll
        for (int kc = 0; kc < 4; ++kc) {
            float4 a0 = make_float4(0.f, 0.f, 0.f, 0.f), a1 = a0;
            if (valid) {
                a0 = *(const float4*)(base + kc * 32);
                a1 = *(const float4*)(base + kc * 32 + 4);
            }
            short8 f;
            f[0] = (short)f2bf(a0.x); f[1] = (short)f2bf(a0.y);
            f[2] = (short)f2bf(a0.z); f[3] = (short)f2bf(a0.w);
            f[4] = (short)f2bf(a1.x); f[5] = (short)f2bf(a1.y);
            f[6] = (short)f2bf(a1.z); f[7] = (short)f2bf(a1.w);
            af[kc] = f;
        }
    } else {
        const uint* X = (const uint*)Xv;
        const uint* base = X + (size_t)arow * 64 + kg * 4;
        #pragma unroll
        for (int kc = 0; kc < 4; ++kc) {
            union { uint4 u; short8 s; } cv;
            cv.u = valid ? *(const uint4*)(base + kc * 16) : make_uint4(0, 0, 0, 0);
            af[kc] = cv.s;
        }
    }

    f32x4 acc[8];
    #pragma unroll
    for (int ct = 0; ct < 8; ++ct) acc[ct] = (f32x4){0.f, 0.f, 0.f, 0.f};

    #pragma unroll
    for (int ct = 0; ct < 8; ++ct) {
        #pragma unroll
        for (int kc = 0; kc < 4; ++kc) {
            union { uint4 u; short8 s; } bv;
            bv.u = *(const uint4*)(Wfrag + ((size_t)(ct * 4 + kc) * 64 + lane) * 4);
            acc[ct] = __builtin_amdgcn_mfma_f32_16x16x32_bf16(af[kc], bv.s, acc[ct], 0, 0, 0);
        }
    }

    // epilogue: D row = kg*4 + reg, col = ct*16 + m
    ushort* ob = (ushort*)out;
    #pragma unroll
    for (int reg = 0; reg < 4; ++reg) {
        int orow = row0 + kg * 4 + reg;
        if (orow < N) {
            float di = dinv[orow];
            size_t rb = (size_t)orow * DIM + m;
            #pragma unroll
            for (int ct = 0; ct < 8; ++ct)
                ob[rb + ct * 16] = f2bf(acc[ct][reg] * di);
        }
    }
}

// ---------------- Aggregation (bf16 rows, f32 accumulate) ----------------

__global__ __launch_bounds__(256) void k_aggregate(const uint* __restrict__ HS,
                                                   const int* __restrict__ rowStart,
                                                   const int* __restrict__ csr,
                                                   const float* __restrict__ dinv,
                                                   const float* __restrict__ bias,
                                                   uint* __restrict__ out, int n) {
    int wv = threadIdx.x >> 6, lane = threadIdx.x & 63;
    int nid = blockIdx.x * 4 + wv;
    if (nid >= n) return;
    uint sv = HS[(size_t)nid * 64 + lane];
    float2 acc = unpack2(sv);
    int beg = rowStart[nid], end = rowStart[nid + 1];
    int e = beg;
    for (; e + 3 < end; e += 4) {
        int s0 = csr[e], s1 = csr[e + 1], s2 = csr[e + 2], s3 = csr[e + 3];
        uint v0 = HS[(size_t)s0 * 64 + lane];
        uint v1 = HS[(size_t)s1 * 64 + lane];
        uint v2 = HS[(size_t)s2 * 64 + lane];
        uint v3 = HS[(size_t)s3 * 64 + lane];
        float2 f0 = unpack2(v0), f1 = unpack2(v1), f2 = unpack2(v2), f3 = unpack2(v3);
        acc.x += (f0.x + f1.x) + (f2.x + f3.x);
        acc.y += (f0.y + f1.y) + (f2.y + f3.y);
    }
    for (; e < end; ++e) {
        uint v0 = HS[(size_t)csr[e] * 64 + lane];
        float2 f0 = unpack2(v0);
        acc.x += f0.x;
        acc.y += f0.y;
    }
    float di = dinv[nid];
    int c = lane * 2;
    float ox = fmaxf(acc.x * di + bias[c], 0.f);
    float oy = fmaxf(acc.y * di + bias[c + 1], 0.f);
    out[(size_t)nid * 64 + lane] = pack2(ox, oy);
}

// ---------------- Pool + head ----------------

__global__ __launch_bounds__(128) void k_pool(const ushort* __restrict__ H,
                                              const int* __restrict__ batch,
                                              const float* __restrict__ Wl,
                                              const float* __restrict__ bl,
                                              float* __restrict__ out, int n) {
    int g = blockIdx.x;
    int lo = 0, hi = n;
    while (lo < hi) { int mid = (lo + hi) >> 1; if (batch[mid] < g) lo = mid + 1; else hi = mid; }
    int s = lo;
    hi = n;
    while (lo < hi) { int mid = (lo + hi) >> 1; if (batch[mid] < g + 1) lo = mid + 1; else hi = mid; }
    int e = lo;

    int d = threadIdx.x;
    float colsum = 0.f;
    for (int i = s; i < e; ++i) colsum += bf2f(H[(size_t)i * DIM + d]);
    float v = colsum * Wl[d];

    #pragma unroll
    for (int off = 32; off > 0; off >>= 1) v += __shfl_down(v, off, 64);
    __shared__ float ws2[2];
    int lane = d & 63, wv = d >> 6;
    if (lane == 0) ws2[wv] = v;
    __syncthreads();
    if (d == 0) {
        float tot = ws2[0] + ws2[1];
        float cntf = (float)(e - s);
        out[g] = tot / fmaxf(cntf, 1.0f) + bl[0];
    }
}

// ---------------- launch ----------------

extern "C" void kernel_launch(void* const* d_in, const int* in_sizes, int n_in,
                              void* d_out, int out_size, void* d_ws, size_t ws_size,
                              hipStream_t stream) {
    const float* x  = (const float*)d_in[0];
    const int*   ei = (const int*)d_in[1];
    const int*   batch = (const int*)d_in[2];
    const float* W1 = (const float*)d_in[3];
    const float* b1 = (const float*)d_in[4];
    const float* W2 = (const float*)d_in[5];
    const float* b2 = (const float*)d_in[6];
    const float* Wl = (const float*)d_in[7];
    const float* bl = (const float*)d_in[8];
    float* out = (float*)d_out;

    // workspace layout (uint units; starts kept 16B-aligned)
    uint* hs  = (uint*)d_ws;                             // N*64 (bf16 x128 rows)
    uint* h2b = hs + (size_t)N_NODES * 64;               // N*64
    float* dinv = (float*)(h2b + (size_t)N_NODES * 64);  // N
    int* rowStart = (int*)(dinv + N_NODES);              // N+4
    int* bucketCnt = rowStart + N_NODES + 4;             // 784
    int* bucketStart = bucketCnt + 784;                  // 784
    int* bucketCursor = bucketStart + 784;               // 784
    int* csr = bucketCursor + 784;                       // E
    uint2* epair = (uint2*)(csr + N_EDGES);              // E pairs (8B aligned)
    uint* wf1 = (uint*)(epair + N_EDGES);                // 8192
    uint* wf2 = wf1 + 8192;                              // 8192

    // 0. weight conversion to MFMA fragment order
    k_wconv<<<64, 256, 0, stream>>>(W1, W2, wf1, wf2);

    // 1. bucketed CSR build
    hipMemsetAsync(bucketCnt, 0, NBUCK * sizeof(int), stream);
    k_bcount<<<64, 1024, 0, stream>>>(ei, bucketCnt, N_EDGES);
    k_bscan<<<1, 1024, 0, stream>>>(bucketCnt, bucketStart, bucketCursor);
    k_bscatter<<<(N_EDGES + SC_CH - 1) / SC_CH, 1024, 0, stream>>>(ei, bucketCursor, epair, N_EDGES);
    k_localcsr<<<NBUCK, 256, 0, stream>>>(epair, bucketStart, rowStart, dinv, csr);

    int strips = (N_NODES + 15) / 16;                    // 3125
    int gemmGrid = (strips + 3) / 4;                     // 782
    int aggGrid  = (N_NODES + 3) / 4;

    // 2. layer 1
    k_lin_mfma<false><<<gemmGrid, 256, 0, stream>>>(x, wf1, dinv, hs, N_NODES);
    k_aggregate<<<aggGrid, 256, 0, stream>>>(hs, rowStart, csr, dinv, b1, h2b, N_NODES);

    // 3. layer 2
    k_lin_mfma<true><<<gemmGrid, 256, 0, stream>>>(h2b, wf2, dinv, hs, N_NODES);
    k_aggregate<<<aggGrid, 256, 0, stream>>>(hs, rowStart, csr, dinv, b2, h2b, N_NODES);

    // 4. pool + head
    k_pool<<<N_GRAPHS, 128, 0, stream>>>((const ushort*)h2b, batch, Wl, bl, out, N_NODES);
}

// Round 6
// 165.221 us; speedup vs baseline: 2.5216x; 1.2002x over previous
//
#include <hip/hip_runtime.h>
#include <hip/hip_bf16.h>

#define N_NODES 50000
#define N_EDGES 800000
#define DIM 128
#define N_GRAPHS 512
#define NBUCK ((N_NODES + 63) / 64)      // 782 buckets of 64 nodes
#define SC_CH 16384                       // edges per scatter block

typedef unsigned int uint;
typedef unsigned short ushort;
typedef __attribute__((ext_vector_type(8))) short short8;   // 8 x bf16 MFMA frag
typedef __attribute__((ext_vector_type(4))) float f32x4;    // MFMA C/D frag

__device__ __forceinline__ ushort f2bf(float f) {
    uint u = __float_as_uint(f);
    uint r = (u + 0x7FFF + ((u >> 16) & 1)) >> 16;   // round-to-nearest-even
    return (ushort)r;
}
__device__ __forceinline__ float bf2f(ushort h) {
    return __uint_as_float(((uint)h) << 16);
}
__device__ __forceinline__ uint pack2(float a, float b) {
    return (uint)f2bf(a) | ((uint)f2bf(b) << 16);
}
__device__ __forceinline__ float2 unpack2(uint v) {
    return make_float2(__uint_as_float(v << 16), __uint_as_float(v & 0xFFFF0000u));
}

// ---------------- misc ----------------

__global__ void k_zero(int* __restrict__ p, int n) {
    int i = blockIdx.x * 256 + threadIdx.x;
    if (i < n) p[i] = 0;
}

// ---------------- bucketed CSR build ----------------

// Pass 1: per-block LDS histogram of dst>>6 -> global bucketCnt
__global__ __launch_bounds__(1024) void k_bcount(const int* __restrict__ ei,
                                                 int* __restrict__ bucketCnt, int E) {
    __shared__ int h[NBUCK];
    int tid = threadIdx.x;
    for (int t = tid; t < NBUCK; t += 1024) h[t] = 0;
    __syncthreads();
    for (int e = blockIdx.x * 1024 + tid; e < E; e += gridDim.x * 1024)
        atomicAdd(&h[ei[E + e] >> 6], 1);
    __syncthreads();
    for (int t = tid; t < NBUCK; t += 1024) {
        int c = h[t];
        if (c) atomicAdd(&bucketCnt[t], c);
    }
}

// Pass 2: single-block scan of NBUCK counts -> bucketStart[NBUCK+1], bucketCursor copy
__global__ __launch_bounds__(1024) void k_bscan(const int* __restrict__ bucketCnt,
                                                int* __restrict__ bucketStart,
                                                int* __restrict__ bucketCursor) {
    __shared__ int wsum[16];
    int tid = threadIdx.x;
    int lane = tid & 63, wv = tid >> 6;
    int v = (tid < NBUCK) ? bucketCnt[tid] : 0;
    int s = v;
    #pragma unroll
    for (int off = 1; off < 64; off <<= 1) {
        int u = __shfl_up(s, off, 64);
        if (lane >= off) s += u;
    }
    if (lane == 63) wsum[wv] = s;
    __syncthreads();
    int woff = 0;
    #pragma unroll
    for (int w = 0; w < 16; ++w) woff += (w < wv) ? wsum[w] : 0;
    int excl = woff + s - v;
    if (tid < NBUCK) {
        bucketStart[tid] = excl;
        bucketCursor[tid] = excl;
    }
    if (tid == 1023) {
        int tot = 0;
        #pragma unroll
        for (int w = 0; w < 16; ++w) tot += wsum[w];
        bucketStart[NBUCK] = tot;
    }
}

// Pass 3: scatter (src,dst) pairs into bucket regions with block-local reservations
__global__ __launch_bounds__(1024) void k_bscatter(const int* __restrict__ ei,
                                                   int* __restrict__ bucketCursor,
                                                   uint2* __restrict__ epair, int E) {
    __shared__ int hc[NBUCK];
    __shared__ int hbase[NBUCK];
    int tid = threadIdx.x;
    int e0 = blockIdx.x * SC_CH;
    int e1 = min(e0 + SC_CH, E);
    for (int t = tid; t < NBUCK; t += 1024) hc[t] = 0;
    __syncthreads();
    for (int e = e0 + tid; e < e1; e += 1024)
        atomicAdd(&hc[ei[E + e] >> 6], 1);
    __syncthreads();
    for (int t = tid; t < NBUCK; t += 1024) {
        int c = hc[t];
        hbase[t] = c ? atomicAdd(&bucketCursor[t], c) : 0;
        hc[t] = 0;
    }
    __syncthreads();
    for (int e = e0 + tid; e < e1; e += 1024) {
        int s = ei[e], d = ei[E + e];
        int b = d >> 6;
        int off = atomicAdd(&hc[b], 1);
        epair[hbase[b] + off] = make_uint2((uint)s, (uint)d);
    }
}

// Pass 4: per-bucket local CSR: rowStart, dinv, csr fill (all writes in a ~4KB window)
__global__ __launch_bounds__(256) void k_localcsr(const uint2* __restrict__ epair,
                                                  const int* __restrict__ bucketStart,
                                                  int* __restrict__ rowStart,
                                                  float* __restrict__ dinv,
                                                  int* __restrict__ csr) {
    __shared__ int cnt[64];
    __shared__ int cur[64];
    int tid = threadIdx.x;
    int b = blockIdx.x;
    int b0 = b << 6;
    int s = bucketStart[b], e = bucketStart[b + 1];
    if (tid < 64) cnt[tid] = 0;
    __syncthreads();
    for (int i = s + tid; i < e; i += 256)
        atomicAdd(&cnt[epair[i].y - b0], 1);
    __syncthreads();
    if (tid < 64) {   // wave 0: 64-wide exclusive scan
        int c = cnt[tid];
        int sc = c;
        #pragma unroll
        for (int off = 1; off < 64; off <<= 1) {
            int u = __shfl_up(sc, off, 64);
            if (tid >= off) sc += u;
        }
        int excl = sc - c;
        int node = b0 + tid;
        if (node < N_NODES) {
            rowStart[node] = s + excl;
            dinv[node] = rsqrtf((float)c + 1.0f);
        }
        cur[tid] = s + excl;
    }
    if (tid == 0 && b == NBUCK - 1) rowStart[N_NODES] = e;
    __syncthreads();
    for (int i = s + tid; i < e; i += 256) {
        uint2 p = epair[i];
        int pos = atomicAdd(&cur[p.y - b0], 1);
        csr[pos] = (int)p.x;
    }
}

// ---------------- W -> MFMA B-fragment order (bf16) ----------------

__global__ __launch_bounds__(256) void k_wconv(const float* __restrict__ W1,
                                               const float* __restrict__ W2,
                                               uint* __restrict__ wf1,
                                               uint* __restrict__ wf2) {
    int t = blockIdx.x * 256 + threadIdx.x;      // [0, 16384)
    const float* W = (t < 8192) ? W1 : W2;
    uint* dst = (t < 8192) ? wf1 : wf2;
    int r = t & 8191;
    int j2 = r & 3;
    int lane = (r >> 2) & 63;
    int tk = r >> 8;                 // ct*4+kc
    int kc = tk & 3, ct = tk >> 2;
    int j = j2 * 2;
    int k = kc * 32 + (lane >> 4) * 8 + j;
    int n = ct * 16 + (lane & 15);
    dst[r] = pack2(W[k * 128 + n], W[(k + 1) * 128 + n]);
}

// ---------------- MFMA GEMM: out_bf16[r,:] = bf16(X[r,:]) @ Wfrag * dinv[r] ----------

template<bool BF16IN>
__global__ __launch_bounds__(256) void k_lin_mfma(const void* __restrict__ Xv,
                                                  const uint* __restrict__ Wfrag,
                                                  const float* __restrict__ dinv,
                                                  uint* __restrict__ out, int N) {
    int wv = threadIdx.x >> 6, lane = threadIdx.x & 63;
    int strip = blockIdx.x * 4 + wv;
    int row0 = strip * 16;
    if (row0 >= N) return;
    int m = lane & 15;        // A-row / D-col within tile
    int kg = lane >> 4;       // k-group
    int arow = row0 + m;
    bool valid = arow < N;

    short8 af[4];
    if constexpr (!BF16IN) {
        const float* X = (const float*)Xv;
        const float* base = X + (size_t)arow * DIM + kg * 8;
        #pragma unroll
        for (int kc = 0; kc < 4; ++kc) {
            float4 a0 = make_float4(0.f, 0.f, 0.f, 0.f), a1 = a0;
            if (valid) {
                a0 = *(const float4*)(base + kc * 32);
                a1 = *(const float4*)(base + kc * 32 + 4);
            }
            short8 f;
            f[0] = (short)f2bf(a0.x); f[1] = (short)f2bf(a0.y);
            f[2] = (short)f2bf(a0.z); f[3] = (short)f2bf(a0.w);
            f[4] = (short)f2bf(a1.x); f[5] = (short)f2bf(a1.y);
            f[6] = (short)f2bf(a1.z); f[7] = (short)f2bf(a1.w);
            af[kc] = f;
        }
    } else {
        const uint* X = (const uint*)Xv;
        const uint* base = X + (size_t)arow * 64 + kg * 4;
        #pragma unroll
        for (int kc = 0; kc < 4; ++kc) {
            union { uint4 u; short8 s; } cv;
            cv.u = valid ? *(const uint4*)(base + kc * 16) : make_uint4(0, 0, 0, 0);
            af[kc] = cv.s;
        }
    }

    f32x4 acc[8];
    #pragma unroll
    for (int ct = 0; ct < 8; ++ct) acc[ct] = (f32x4){0.f, 0.f, 0.f, 0.f};

    #pragma unroll
    for (int ct = 0; ct < 8; ++ct) {
        #pragma unroll
        for (int kc = 0; kc < 4; ++kc) {
            union { uint4 u; short8 s; } bv;
            bv.u = *(const uint4*)(Wfrag + ((size_t)(ct * 4 + kc) * 64 + lane) * 4);
            acc[ct] = __builtin_amdgcn_mfma_f32_16x16x32_bf16(af[kc], bv.s, acc[ct], 0, 0, 0);
        }
    }

    // epilogue: D row = kg*4 + reg, col = ct*16 + m
    ushort* ob = (ushort*)out;
    #pragma unroll
    for (int reg = 0; reg < 4; ++reg) {
        int orow = row0 + kg * 4 + reg;
        if (orow < N) {
            float di = dinv[orow];
            size_t rb = (size_t)orow * DIM + m;
            #pragma unroll
            for (int ct = 0; ct < 8; ++ct)
                ob[rb + ct * 16] = f2bf(acc[ct][reg] * di);
        }
    }
}

// ---------------- Aggregation (bf16 rows, f32 accumulate) ----------------
// FUSE_HEAD=false: write post-relu row as bf16.
// FUSE_HEAD=true : write y[nid] = relu_row . Wl  (head dot-product), no row write.

template<bool FUSE_HEAD>
__global__ __launch_bounds__(256) void k_aggregate(const uint* __restrict__ HS,
                                                   const int* __restrict__ rowStart,
                                                   const int* __restrict__ csr,
                                                   const float* __restrict__ dinv,
                                                   const float* __restrict__ bias,
                                                   const float* __restrict__ Wl,
                                                   uint* __restrict__ outRow,
                                                   float* __restrict__ outY, int n) {
    int wv = threadIdx.x >> 6, lane = threadIdx.x & 63;
    int nid = blockIdx.x * 4 + wv;
    if (nid >= n) return;
    uint sv = HS[(size_t)nid * 64 + lane];
    float2 acc = unpack2(sv);
    int beg = rowStart[nid], end = rowStart[nid + 1];
    int e = beg;
    for (; e + 3 < end; e += 4) {
        int s0 = csr[e], s1 = csr[e + 1], s2 = csr[e + 2], s3 = csr[e + 3];
        uint v0 = HS[(size_t)s0 * 64 + lane];
        uint v1 = HS[(size_t)s1 * 64 + lane];
        uint v2 = HS[(size_t)s2 * 64 + lane];
        uint v3 = HS[(size_t)s3 * 64 + lane];
        float2 f0 = unpack2(v0), f1 = unpack2(v1), f2 = unpack2(v2), f3 = unpack2(v3);
        acc.x += (f0.x + f1.x) + (f2.x + f3.x);
        acc.y += (f0.y + f1.y) + (f2.y + f3.y);
    }
    for (; e < end; ++e) {
        uint v0 = HS[(size_t)csr[e] * 64 + lane];
        float2 f0 = unpack2(v0);
        acc.x += f0.x;
        acc.y += f0.y;
    }
    float di = dinv[nid];
    int c = lane * 2;
    float ox = fmaxf(acc.x * di + bias[c], 0.f);
    float oy = fmaxf(acc.y * di + bias[c + 1], 0.f);
    if constexpr (!FUSE_HEAD) {
        outRow[(size_t)nid * 64 + lane] = pack2(ox, oy);
    } else {
        float part = ox * Wl[c] + oy * Wl[c + 1];
        #pragma unroll
        for (int off = 32; off > 0; off >>= 1) part += __shfl_down(part, off, 64);
        if (lane == 0) outY[nid] = part;
    }
}

// ---------------- Pool over per-node head values ----------------

__global__ __launch_bounds__(64) void k_pool_y(const float* __restrict__ y,
                                               const int* __restrict__ batch,
                                               const float* __restrict__ bl,
                                               float* __restrict__ out, int n) {
    int g = blockIdx.x;
    int lane = threadIdx.x;
    int lo = 0, hi = n;
    while (lo < hi) { int mid = (lo + hi) >> 1; if (batch[mid] < g) lo = mid + 1; else hi = mid; }
    int s = lo;
    hi = n;
    while (lo < hi) { int mid = (lo + hi) >> 1; if (batch[mid] < g + 1) lo = mid + 1; else hi = mid; }
    int e = lo;

    float sum = 0.f;
    for (int i = s + lane; i < e; i += 64) sum += y[i];
    #pragma unroll
    for (int off = 32; off > 0; off >>= 1) sum += __shfl_down(sum, off, 64);
    if (lane == 0) out[g] = sum / fmaxf((float)(e - s), 1.0f) + bl[0];
}

// ---------------- launch ----------------

extern "C" void kernel_launch(void* const* d_in, const int* in_sizes, int n_in,
                              void* d_out, int out_size, void* d_ws, size_t ws_size,
                              hipStream_t stream) {
    const float* x  = (const float*)d_in[0];
    const int*   ei = (const int*)d_in[1];
    const int*   batch = (const int*)d_in[2];
    const float* W1 = (const float*)d_in[3];
    const float* b1 = (const float*)d_in[4];
    const float* W2 = (const float*)d_in[5];
    const float* b2 = (const float*)d_in[6];
    const float* Wl = (const float*)d_in[7];
    const float* bl = (const float*)d_in[8];
    float* out = (float*)d_out;

    // workspace layout (uint units; starts kept 16B-aligned)
    uint* hs  = (uint*)d_ws;                             // N*64 (bf16 x128 rows)
    uint* h2b = hs + (size_t)N_NODES * 64;               // N*64
    float* dinv = (float*)(h2b + (size_t)N_NODES * 64);  // N
    float* ynode = dinv + N_NODES;                       // N
    int* rowStart = (int*)(ynode + N_NODES);             // N+4
    int* bucketCnt = rowStart + N_NODES + 4;             // 784
    int* bucketStart = bucketCnt + 784;                  // 784
    int* bucketCursor = bucketStart + 784;               // 784
    int* csr = bucketCursor + 784;                       // E
    uint2* epair = (uint2*)(csr + N_EDGES);              // E pairs (8B aligned)
    uint* wf1 = (uint*)(epair + N_EDGES);                // 8192
    uint* wf2 = wf1 + 8192;                              // 8192

    // 0. weight conversion to MFMA fragment order
    k_wconv<<<64, 256, 0, stream>>>(W1, W2, wf1, wf2);

    // 1. bucketed CSR build
    k_zero<<<(NBUCK + 255) / 256, 256, 0, stream>>>(bucketCnt, NBUCK);
    k_bcount<<<64, 1024, 0, stream>>>(ei, bucketCnt, N_EDGES);
    k_bscan<<<1, 1024, 0, stream>>>(bucketCnt, bucketStart, bucketCursor);
    k_bscatter<<<(N_EDGES + SC_CH - 1) / SC_CH, 1024, 0, stream>>>(ei, bucketCursor, epair, N_EDGES);
    k_localcsr<<<NBUCK, 256, 0, stream>>>(epair, bucketStart, rowStart, dinv, csr);

    int strips = (N_NODES + 15) / 16;                    // 3125
    int gemmGrid = (strips + 3) / 4;                     // 782
    int aggGrid  = (N_NODES + 3) / 4;

    // 2. layer 1
    k_lin_mfma<false><<<gemmGrid, 256, 0, stream>>>(x, wf1, dinv, hs, N_NODES);
    k_aggregate<false><<<aggGrid, 256, 0, stream>>>(hs, rowStart, csr, dinv, b1, Wl, h2b, ynode, N_NODES);

    // 3. layer 2 (head fused into aggregation)
    k_lin_mfma<true><<<gemmGrid, 256, 0, stream>>>(h2b, wf2, dinv, hs, N_NODES);
    k_aggregate<true><<<aggGrid, 256, 0, stream>>>(hs, rowStart, csr, dinv, b2, Wl, h2b, ynode, N_NODES);

    // 4. pool + head bias
    k_pool_y<<<N_GRAPHS, 64, 0, stream>>>(ynode, batch, bl, out, N_NODES);
}